// Round 18
// baseline (737.465 us; speedup 1.0000x reference)
//
#include <hip/hip_runtime.h>
#include <hip/hip_bf16.h>
#include <math.h>

// ---------------------------------------------------------------------------
// CapsNet forward. R18 = R17 + route v8: 1 image/block (grid 2560), bf16
// priors in LDS (36.9KB) -> 4 blocks/CU, 32 waves. R17 evidence: 2 blocks/CU
// only bought ~20us; route's short barrier-separated phases need more
// co-resident blocks to hide. rwT re-read/XCD grows to ~151MB (L2, ~35us) —
// paid for by 2x occupancy. absmax unchanged by bf16 priors (R17 measured).
// ---------------------------------------------------------------------------

typedef __attribute__((ext_vector_type(8))) short bf16x8;
typedef __attribute__((ext_vector_type(4))) float f32x4;

__device__ __forceinline__ void gl16(const void* g, void* l) {
  __builtin_amdgcn_global_load_lds((const __attribute__((address_space(1))) void*)g,
                                   (__attribute__((address_space(3))) void*)l,
                                   16, 0, 0);
}

__device__ __forceinline__ float bfl(unsigned u) {   // low bf16 -> float
  union { unsigned x; float f; } c; c.x = u << 16; return c.f;
}
__device__ __forceinline__ float bfh(unsigned u) {   // high bf16 -> float
  union { unsigned x; float f; } c; c.x = u & 0xffff0000u; return c.f;
}
__device__ __forceinline__ unsigned bpk(float a, float b) {
  const __hip_bfloat16 ha = __float2bfloat16(a), hb = __float2bfloat16(b);
  union { __hip_bfloat16 h; unsigned short s; } ca, cb;
  ca.h = ha; cb.h = hb;
  return (unsigned)ca.s | ((unsigned)cb.s << 16);
}

// ==== k_prep: [0,2688) wrep | [2688,2868) rrep | [2868,3892) conv1 =========
__global__ __launch_bounds__(256) void k_prep(
    const float* __restrict__ pw, __hip_bfloat16* __restrict__ wGp,
    const float* __restrict__ rw, float* __restrict__ rwT,
    const float* __restrict__ x, const float* __restrict__ c1w,
    const float* __restrict__ c1b, __hip_bfloat16* __restrict__ hT) {
  __shared__ __attribute__((aligned(16))) char smem[44480];
  const int bid = blockIdx.x;
  const int t = threadIdx.x;
  if (bid < 2688) {                                 // ---- wrep ----
    const int s = bid >> 2, ocq = bid & 3;          // s in [0,672)
    const int ch = s / 21, tq = s - ch * 21;
    __hip_bfloat16* outp = wGp + ((size_t)s * 4 + ocq) * 4608;
    for (int e = t; e < 2048; e += 256) {
      const int ocl = e >> 5, k = e & 31;
      const int tapl = k >> 3, icl = k & 7;
      const int tap = tq * 4 + tapl, ic = ch * 8 + icl;
      const int oc = ocq * 64 + ocl;
      const float v = (tap < 81) ? pw[((size_t)oc * 256 + ic) * 81 + tap] : 0.f;
      const __hip_bfloat16 hi = __float2bfloat16(v);
      const __hip_bfloat16 lo = __float2bfloat16(v - __bfloat162float(hi));
      outp[ocl * 72 + k] = hi;
      outp[ocl * 72 + 32 + k] = lo;
    }
    for (int e = t; e < 512; e += 256) {
      const int ocl = e >> 3, j = e & 7;
      outp[ocl * 72 + 64 + j] = __float2bfloat16(0.f);
    }
  } else if (bid < 2868) {                          // ---- rrep ----
    // rw[o][i][c][d] -> rwT2[o][c*4+dq][i][4]  (d = dq*4+dl)
    float* tile = (float*)smem;                     // 64*129 floats (33KB)
    const int bb = bid - 2688;
    const int o = bb / 18, ig = bb % 18;
    for (int idx = t; idx < 64 * 128; idx += 256) {
      const int i = idx >> 7, cd = idx & 127;
      tile[i * 129 + cd] = rw[((size_t)o * 1152 + ig * 64 + i) * 128 + cd];
    }
    __syncthreads();
    const int il = t >> 2, dl = t & 3;              // 256 thr = 64 il x 4 dl
#pragma unroll 1
    for (int cdq = 0; cdq < 32; cdq++) {            // 1KB contiguous writes
      const int c = cdq >> 2, dq = cdq & 3;
      rwT[((size_t)(o * 32 + cdq) * 1152 + ig * 64 + il) * 4 + dl] =
          tile[il * 129 + c * 16 + dq * 4 + dl];
    }
  } else {                                          // ---- conv1 ----
    const int bb = bid - 2868;
    const int img = bb >> 2, ocq = bb & 3;          // 64 oc per block
    float* xs = (float*)smem;                       // 784 f
    float* ws = xs + 784;                           // 5184 f
    __hip_bfloat16* tile = (__hip_bfloat16*)(ws + 5184);  // 8*1288 bf16
    const float4* xg = (const float4*)(x + (size_t)img * 784);
    if (t < 196) ((float4*)xs)[t] = xg[t];
    const float4* wg = (const float4*)(c1w + (size_t)ocq * 64 * 81);
    for (int i = t; i < 1296; i += 256) ((float4*)ws)[i] = wg[i];
    __syncthreads();
    const int ocl = t & 63, rowg = t >> 6;          // wave = rowg
    const int oc = ocq * 64 + ocl;
    const int chl = ocl >> 3, icl = ocl & 7;
    const float bv = c1b[oc];
    __hip_bfloat16* hb = hT + ((size_t)img * 32 + ocq * 8) * 6560;
#pragma unroll 1
    for (int it = 0; it < 5; it++) {
      const int r = it * 4 + rowg;                  // y
      float acc[20];
#pragma unroll
      for (int p = 0; p < 20; p++) acc[p] = bv;
#pragma unroll
      for (int ky = 0; ky < 9; ky++) {
        float xr[28];
        const float* xrow = &xs[(r + ky) * 28];
#pragma unroll
        for (int q = 0; q < 7; q++) ((float4*)xr)[q] = ((const float4*)xrow)[q];
        float wr[9];
#pragma unroll
        for (int i = 0; i < 9; i++) wr[i] = ws[ocl * 81 + ky * 9 + i];
#pragma unroll
        for (int kx = 0; kx < 9; kx++)
#pragma unroll
          for (int p = 0; p < 20; p++)
            acc[p] = fmaf(wr[kx], xr[p + kx], acc[p]);
      }
#pragma unroll
      for (int p = 0; p < 20; p++) {                // p = x
        const float v = fmaxf(acc[p], 0.f);
        const __hip_bfloat16 hi = __float2bfloat16(v);
        const __hip_bfloat16 lo = __float2bfloat16(v - __bfloat162float(hi));
        tile[chl * 1288 + (p * 8 + rowg * 2) * 8 + icl] = hi;
        tile[chl * 1288 + (p * 8 + rowg * 2 + 1) * 8 + icl] = lo;
      }
      __syncthreads();
#pragma unroll
      for (int q = 0; q < 5; q++) {                 // 1280 16B chunks
        const int idx = q * 256 + t;
        const int c2 = idx / 160, rem = idx - c2 * 160;
        const int xx = rem >> 3, j = rem & 7;
        const float4 vdat = *(const float4*)&tile[c2 * 1288 + rem * 8];
        *(float4*)(hb + (size_t)c2 * 6560 + (size_t)(xx * 41 + it * 8 + j) * 8) = vdat;
      }
      __syncthreads();
    }
  }
}

// ====== conv2 MFMA (R13): pq[kq][img][px36][oc256] partial over 16 ch ======
#define HT_B 52480              // 3280 chunks x 16B  (4 img x 820)
#define PQ_F 2359296
__global__ __launch_bounds__(512) void k_conv2(
    const __hip_bfloat16* __restrict__ hTg,    // [chunk img][32ch][820ch][8]
    const __hip_bfloat16* __restrict__ wGp,    // [672][4ocq][4608B] (+1 pad step)
    float* __restrict__ pq, int c0) {
  __shared__ char hT[HT_B];
  const int bid = blockIdx.x;
  int ig, ocq, kq;
  if (gridDim.x == 512) {       // XCD swizzle: ocq sharers keep bid%8
    ig = (bid & 7) | (((bid >> 5) & 7) << 3);
    ocq = (bid >> 3) & 3;
    kq = bid >> 8;
  } else {
    ig = bid >> 3;
    ocq = (bid >> 1) & 3;
    kq = bid & 1;
  }
  const int t = threadIdx.x;
  const int w = t >> 6, lane = t & 63;
  const int lquad = lane >> 4, lrow = lane & 15;
  const int mhalf = w >> 2;
  const int nt = mhalf ? 4 : 5;
  const int mtb = mhalf ? 5 : 0;
  const int ocg = ocq * 64 + (w & 3) * 16 + lrow;
  int abase[5];
#pragma unroll
  for (int i = 0; i < 5; i++) {
    int m = (mtb + i) * 16 + lrow;
    if (i >= nt) m = 0;
    const int img = m / 36, px = m - img * 36;
    const int oy = px / 6, ox = px - oy * 6;
    abase[i] = img * 13120 + ox * 1312 + oy * 64;   // bytes in hT
  }
  f32x4 acc[5];
#pragma unroll
  for (int i = 0; i < 5; i++) acc[i] = (f32x4){0.f, 0.f, 0.f, 0.f};

  const char* hgc = (const char*)hTg;
  const char* wp = (const char*)wGp + ((size_t)(kq * 336) * 4 + ocq) * 4608 +
                   ((w & 3) * 16 + lrow) * 144 + lquad * 16;
  bf16x8 bh = *(const bf16x8*)wp;
  bf16x8 bl = *(const bf16x8*)(wp + 64);
  wp += 18432;
#pragma unroll 1
  for (int chl = 0; chl < 16; chl++) {
    const int ch = kq * 16 + chl;
    const char* hch = hgc + ((size_t)(ig * 128) + ch) * 13120;
#pragma unroll
    for (int rr = 0; rr < 6; rr++) {
      const int idx = t + rr * 512;
      const int j = idx / 820, r = idx - j * 820;
      gl16(hch + (size_t)j * 419840 + r * 16, hT + rr * 8192 + w * 1024);
    }
    if (t < 208) {
      const int idx = 3072 + t;
      const int j = idx / 820, r = idx - j * 820;
      gl16(hch + (size_t)j * 419840 + r * 16, hT + 49152 + w * 1024);
    }
    __syncthreads();
#pragma unroll 1
    for (int tq = 0; tq < 21; tq++) {
      const bf16x8 nh = *(const bf16x8*)wp;         // prefetch next step's W
      const bf16x8 nl = *(const bf16x8*)(wp + 64);
      wp += 18432;
      const int tt = tq * 4 + lquad;                // this quad's tap
      const int ky = tt / 9, kx = tt - ky * 9;
      const int toff = kx * 656 + ky * 32;          // (kx*41 + ky*2) chunks
      bf16x8 ah[5];
#pragma unroll
      for (int i = 0; i < 5; i++)
        ah[i] = *(const bf16x8*)(hT + abase[i] + toff);
#pragma unroll
      for (int i = 0; i < 5; i++)
        if (i < nt) acc[i] = __builtin_amdgcn_mfma_f32_16x16x32_bf16(ah[i], bh, acc[i], 0, 0, 0);
#pragma unroll
      for (int i = 0; i < 5; i++)
        if (i < nt) acc[i] = __builtin_amdgcn_mfma_f32_16x16x32_bf16(ah[i], bl, acc[i], 0, 0, 0);
      bf16x8 al[5];
#pragma unroll
      for (int i = 0; i < 5; i++)
        al[i] = *(const bf16x8*)(hT + abase[i] + toff + 16);
#pragma unroll
      for (int i = 0; i < 5; i++)
        if (i < nt) acc[i] = __builtin_amdgcn_mfma_f32_16x16x32_bf16(al[i], bh, acc[i], 0, 0, 0);
      bh = nh;
      bl = nl;
    }
    __syncthreads();                                // hT reuse fence
  }
  float* pblk = pq + (size_t)kq * PQ_F;
#pragma unroll
  for (int i = 0; i < 5; i++) {
    if (i < nt) {
#pragma unroll
      for (int r = 0; r < 4; r++) {
        const int m = (mtb + i) * 16 + lquad * 4 + r;   // D row = quad*4+reg
        const int img = m / 36, px = m - img * 36;
        pblk[((size_t)(c0 + ig * 4 + img) * 36 + px) * 256 + ocg] = acc[i][r];
      }
    }
  }
}

// ===== squash v2: block/b, LDS-staged coalesced ============================
__global__ __launch_bounds__(256) void k_squash(const float* __restrict__ pq,
                                                const float* __restrict__ bias,
                                                float* __restrict__ u) {
  const int b = blockIdx.x;
  __shared__ float ps[36 * 257];
  const int t = threadIdx.x;
  const float4* s0 = (const float4*)(pq + (size_t)b * 9216);
  const float4* s1 = (const float4*)(pq + (size_t)PQ_F + (size_t)b * 9216);
#pragma unroll
  for (int q = 0; q < 9; q++) {                     // 2304 float4, coalesced
    const int idx = q * 256 + t;
    const float4 a = s0[idx], c = s1[idx];
    const int px = idx >> 6, oc = (idx & 63) * 4;
    float* dst = &ps[px * 257 + oc];
    dst[0] = a.x + c.x; dst[1] = a.y + c.y;
    dst[2] = a.z + c.z; dst[3] = a.w + c.w;
  }
  __syncthreads();
#pragma unroll
  for (int rr = 0; rr < 5; rr++) {
    const int i = rr * 256 + t;
    if (i < 1152) {
      const int cp = i / 36, px = i - cp * 36;
      float s[8], sq = 0.f;
#pragma unroll
      for (int d = 0; d < 8; d++) {
        s[d] = ps[px * 257 + d * 32 + cp] + bias[d * 32 + cp];
        sq = fmaf(s[d], s[d], sq);
      }
      const float scale = sq / ((1.f + sq) * sqrtf(sq));
      float o[8];
#pragma unroll
      for (int d = 0; d < 8; d++) o[d] = s[d] * scale;
      float* ub = u + ((size_t)b * 1152 + i) * 8;
      ((float4*)ub)[0] = ((float4*)o)[0];
      ((float4*)ub)[1] = ((float4*)o)[1];
    }
  }
}

// ======================= routing by agreement ==============================
__device__ __forceinline__ float wsum(float v) {
#pragma unroll
  for (int o = 32; o > 0; o >>= 1) v += __shfl_xor(v, o, 64);
  return v;
}
__device__ __forceinline__ float wmaxr(float v) {
#pragma unroll
  for (int o = 32; o > 0; o >>= 1) v = fmaxf(v, __shfl_xor(v, o, 64));
  return v;
}

// route v8: 1 img/block (grid 2560), priors bf16-packed in LDS (36.9KB) ->
// 4 blocks/CU. rwT2 b128 global loads. XCD-o-affinity swizzle.
__global__ __launch_bounds__(512, 4) void k_route(const float* __restrict__ u,
                                                  const float* __restrict__ rwT,
                                                  float* __restrict__ vecs) {
  const int bid = blockIdx.x;
  int o, b;
  if (bid < 2048) { o = bid & 7; b = bid >> 3; }         // XCD k gets o=k
  else { const int ix = bid - 2048; o = 8 + (ix & 1); b = ix >> 1; }
  __shared__ __attribute__((aligned(16))) unsigned priB[4608 * 2];  // 36.9KB
  __shared__ float red[8 * 17];
  __shared__ float redm[8];
  const int t = threadIdx.x;
  const int wave = t >> 6, lane = t & 63;
  const float* rwo = rwT + (size_t)(o * 32) * 4608;      // [cdq32][1152][4]
  const float* ub = u + (size_t)b * 9216;
  // ---- priors (fp32 compute) -> bf16-packed LDS ----
#pragma unroll
  for (int ci = 0; ci < 3; ci++) {
    const bool valid = (ci < 2) || (t < 128);
    const int i = valid ? (t + ci * 512) : 0;
    float uv[8];
    *(float4*)&uv[0] = *(const float4*)(ub + i * 8);
    *(float4*)&uv[4] = *(const float4*)(ub + i * 8 + 4);
    float a[16];
#pragma unroll
    for (int d = 0; d < 16; d++) a[d] = 0.f;
#pragma unroll
    for (int c = 0; c < 8; c++) {
#pragma unroll
      for (int dq = 0; dq < 4; dq++) {
        const float4 wv = *(const float4*)(rwo + (size_t)(c * 4 + dq) * 4608 + i * 4);
        a[dq * 4 + 0] = fmaf(uv[c], wv.x, a[dq * 4 + 0]);
        a[dq * 4 + 1] = fmaf(uv[c], wv.y, a[dq * 4 + 1]);
        a[dq * 4 + 2] = fmaf(uv[c], wv.z, a[dq * 4 + 2]);
        a[dq * 4 + 3] = fmaf(uv[c], wv.w, a[dq * 4 + 3]);
      }
    }
    if (valid) {
#pragma unroll
      for (int dq = 0; dq < 4; dq++) {
        uint2 p;
        p.x = bpk(a[dq * 4 + 0], a[dq * 4 + 1]);
        p.y = bpk(a[dq * 4 + 2], a[dq * 4 + 3]);
        *(uint2*)&priB[(dq * 1152 + i) * 2] = p;    // 8B dense -> no conflict
      }
    }
  }
  __syncthreads();
  float l[3];
#pragma unroll
  for (int ci = 0; ci < 3; ci++)
    l[ci] = ((ci < 2) || (t < 128)) ? 0.f : -1e30f;
  float v[16];
#pragma unroll 1
  for (int it = 0; it < 3; it++) {
    float m = wmaxr(fmaxf(fmaxf(l[0], l[1]), l[2]));
    if (lane == 0) redm[wave] = m;
    __syncthreads();
    m = redm[0];
#pragma unroll
    for (int wv2 = 1; wv2 < 8; wv2++) m = fmaxf(m, redm[wv2]);
    float Z = 0.f, S[16];
#pragma unroll
    for (int d = 0; d < 16; d++) S[d] = 0.f;
#pragma unroll
    for (int ci = 0; ci < 3; ci++) {
      const bool valid = (ci < 2) || (t < 128);
      const int i = valid ? (t + ci * 512) : 0;
      const float e = expf(l[ci] - m);               // 0 for dummies
      Z += e;
#pragma unroll
      for (int dq = 0; dq < 4; dq++) {
        const uint2 w = *(const uint2*)&priB[(dq * 1152 + i) * 2];
        S[dq * 4 + 0] = fmaf(e, bfl(w.x), S[dq * 4 + 0]);
        S[dq * 4 + 1] = fmaf(e, bfh(w.x), S[dq * 4 + 1]);
        S[dq * 4 + 2] = fmaf(e, bfl(w.y), S[dq * 4 + 2]);
        S[dq * 4 + 3] = fmaf(e, bfh(w.y), S[dq * 4 + 3]);
      }
    }
    Z = wsum(Z);
#pragma unroll
    for (int d = 0; d < 16; d++) S[d] = wsum(S[d]);
    __syncthreads();                                 // red reuse fence
    if (lane == 0) {
      red[wave * 17] = Z;
#pragma unroll
      for (int d = 0; d < 16; d++) red[wave * 17 + 1 + d] = S[d];
    }
    __syncthreads();
    float Zt = 0.f;
#pragma unroll
    for (int wv2 = 0; wv2 < 8; wv2++) Zt += red[wv2 * 17];
    float sq = 0.f;
#pragma unroll
    for (int d = 0; d < 16; d++) {
      float sd = 0.f;
#pragma unroll
      for (int wv2 = 0; wv2 < 8; wv2++) sd += red[wv2 * 17 + 1 + d];
      sd /= Zt;
      v[d] = sd;
      sq = fmaf(sd, sd, sq);
    }
    const float scale = sq / ((1.f + sq) * sqrtf(sq));
#pragma unroll
    for (int d = 0; d < 16; d++) v[d] *= scale;
    if (it < 2) {
#pragma unroll
      for (int ci = 0; ci < 3; ci++) {
        const bool valid = (ci < 2) || (t < 128);
        const int i = valid ? (t + ci * 512) : 0;
        float dot = 0.f;
#pragma unroll
        for (int dq = 0; dq < 4; dq++) {
          const uint2 w = *(const uint2*)&priB[(dq * 1152 + i) * 2];
          dot = fmaf(bfl(w.x), v[dq * 4 + 0], dot);
          dot = fmaf(bfh(w.x), v[dq * 4 + 1], dot);
          dot = fmaf(bfl(w.y), v[dq * 4 + 2], dot);
          dot = fmaf(bfh(w.y), v[dq * 4 + 3], dot);
        }
        l[ci] += dot;
      }
    }
  }
  if (t == 0) {
    float* vb = vecs + ((size_t)b * 10 + o) * 16;
#pragma unroll
    for (int d = 0; d < 16; d++) vb[d] = v[d];
  }
}

// ====== dec1 (cls fused): classes softmax/argmax + first decoder layer =====
__global__ __launch_bounds__(512) void k_dec1(const float* __restrict__ vecs,
                                              const float* __restrict__ w1,
                                              const float* __restrict__ b1,
                                              float* __restrict__ out,
                                              float* __restrict__ h1) {
  const int b = blockIdx.x, t = threadIdx.x;
  __shared__ float vbs[160];
  __shared__ float sv[16];
  __shared__ int ams;
  const float* vb = vecs + (size_t)b * 160;
  if (t < 160) vbs[t] = vb[t];                      // coalesced
  __syncthreads();
  if (t == 0) {
    float nrm[10];
#pragma unroll
    for (int o = 0; o < 10; o++) {
      float sq = 0.f;
#pragma unroll
      for (int d = 0; d < 16; d++) { const float xv = vbs[o * 16 + d]; sq = fmaf(xv, xv, sq); }
      nrm[o] = sqrtf(sq);
    }
    float m = nrm[0];
#pragma unroll
    for (int o = 1; o < 10; o++) m = fmaxf(m, nrm[o]);
    float e[10], Z = 0.f;
#pragma unroll
    for (int o = 0; o < 10; o++) { e[o] = expf(nrm[o] - m); Z += e[o]; }
    const float inv = 1.f / Z;
    int am = 0;
    float best = e[0] * inv;
#pragma unroll
    for (int o = 0; o < 10; o++) {
      const float c = e[o] * inv;
      out[(size_t)b * 10 + o] = c;
      if (o > 0 && c > best) { best = c; am = o; }  // strict >: first-max
    }
    ams = am;
  }
  __syncthreads();
  const int am2 = ams;
  if (t < 16) sv[t] = vbs[am2 * 16 + t];
  __syncthreads();
  const float* wrow = w1 + (size_t)am2 * 16 * 512;
  float acc = b1[t];
#pragma unroll
  for (int d = 0; d < 16; d++) acc = fmaf(sv[d], wrow[d * 512 + t], acc);
  h1[(size_t)b * 512 + t] = fmaxf(acc, 0.f);
}

// dec2 v2: 2 imgs x 128 n per block (grid 1024); w2 in 32-k LDS tiles.
__global__ __launch_bounds__(128) void k_dec2(const float* __restrict__ h1,
                                              const float* __restrict__ w2,
                                              const float* __restrict__ b2,
                                              float* __restrict__ h2) {
  const int nc = blockIdx.x >> 7, bg = blockIdx.x & 127;
  const int t = threadIdx.x;
  const int n = nc * 128 + t;
  const int bs = bg * 2;
  __shared__ float h1s[2 * 512];
  __shared__ float wts[32 * 128];
  {
    const float4* src = (const float4*)(h1 + (size_t)bs * 512);
    for (int i = t; i < 256; i += 128) ((float4*)h1s)[i] = src[i];
  }
  float acc[2];
  const float bb = b2[n];
  acc[0] = bb; acc[1] = bb;
#pragma unroll 1
  for (int kt = 0; kt < 16; kt++) {
    __syncthreads();
#pragma unroll
    for (int r = 0; r < 32; r++)
      wts[r * 128 + t] = w2[(size_t)(kt * 32 + r) * 1024 + n];
    __syncthreads();
#pragma unroll
    for (int k4 = 0; k4 < 8; k4++) {
      float wq[4];
#pragma unroll
      for (int q = 0; q < 4; q++) wq[q] = wts[(k4 * 4 + q) * 128 + t];
#pragma unroll
      for (int j = 0; j < 2; j++) {
        const float4 hv = *(const float4*)&h1s[j * 512 + kt * 32 + k4 * 4];
        acc[j] = fmaf(hv.x, wq[0], acc[j]);
        acc[j] = fmaf(hv.y, wq[1], acc[j]);
        acc[j] = fmaf(hv.z, wq[2], acc[j]);
        acc[j] = fmaf(hv.w, wq[3], acc[j]);
      }
    }
  }
#pragma unroll
  for (int j = 0; j < 2; j++) h2[(size_t)(bs + j) * 1024 + n] = fmaxf(acc[j], 0.f);
}

// dec3 v2: 2 imgs x 112 n per block (grid 896); w3 in 32-k LDS tiles.
__global__ __launch_bounds__(128) void k_dec3(const float* __restrict__ h2,
                                              const float* __restrict__ w3,
                                              const float* __restrict__ b3,
                                              float* __restrict__ out) {
  const int nc = blockIdx.x >> 7, bg = blockIdx.x & 127;
  const int t = threadIdx.x;
  const int bs = bg * 2;
  __shared__ float h2s[2 * 1024];
  __shared__ float wts[32 * 112];
  {
    const float4* src = (const float4*)(h2 + (size_t)bs * 1024);
    for (int i = t; i < 512; i += 128) ((float4*)h2s)[i] = src[i];
  }
  const int n = nc * 112 + (t < 112 ? t : 0);
  float acc[2];
  const float bb = b3[n];
  acc[0] = bb; acc[1] = bb;
#pragma unroll 1
  for (int kt = 0; kt < 32; kt++) {
    __syncthreads();
#pragma unroll
    for (int r = 0; r < 32; r++)
      if (t < 112) wts[r * 112 + t] = w3[(size_t)(kt * 32 + r) * 784 + n];
    __syncthreads();
    if (t < 112) {
#pragma unroll
      for (int k4 = 0; k4 < 8; k4++) {
        float wq[4];
#pragma unroll
        for (int q = 0; q < 4; q++) wq[q] = wts[(k4 * 4 + q) * 112 + t];
#pragma unroll
        for (int j = 0; j < 2; j++) {
          const float4 hv = *(const float4*)&h2s[j * 1024 + kt * 32 + k4 * 4];
          acc[j] = fmaf(hv.x, wq[0], acc[j]);
          acc[j] = fmaf(hv.y, wq[1], acc[j]);
          acc[j] = fmaf(hv.z, wq[2], acc[j]);
          acc[j] = fmaf(hv.w, wq[3], acc[j]);
        }
      }
    }
  }
  if (t < 112) {
#pragma unroll
    for (int j = 0; j < 2; j++)
      out[(size_t)(bs + j) * 784 + n] = 1.f / (1.f + expf(-acc[j]));
  }
}

// ============================= launcher ====================================
extern "C" void kernel_launch(void* const* d_in, const int* in_sizes, int n_in,
                              void* d_out, int out_size, void* d_ws, size_t ws_size,
                              hipStream_t stream) {
  const float* x   = (const float*)d_in[0];
  const float* c1w = (const float*)d_in[1];
  const float* c1b = (const float*)d_in[2];
  const float* pw  = (const float*)d_in[3];
  const float* pb  = (const float*)d_in[4];
  const float* rw  = (const float*)d_in[5];
  const float* w1  = (const float*)d_in[6];
  const float* b1  = (const float*)d_in[7];
  const float* w2  = (const float*)d_in[8];
  const float* b2  = (const float*)d_in[9];
  const float* w3  = (const float*)d_in[10];
  const float* b3  = (const float*)d_in[11];
  float* out = (float*)d_out;
  float* ws = (float*)d_ws;

  const size_t WGP_F = ((size_t)672 * 4 * 4608 + 18432) / 4;
  const size_t U_F = 2359296;
  const size_t RWT_F = 10 * 32 * 4608;                 // rwT2 layout
  const size_t SMALL_F = 40960 + 4096 + 256 + 131072 + 262144;
  const size_t fixed_f = WGP_F + 2 * PQ_F + U_F + RWT_F + SMALL_F;
  int chunk = 256;
  while (chunk > 8 && (fixed_f + (size_t)chunk * 104960) * 4 > ws_size) chunk >>= 1;

  __hip_bfloat16* wGp  = (__hip_bfloat16*)ws;
  __hip_bfloat16* hTgc = (__hip_bfloat16*)(ws + WGP_F);
  float* pq   = ws + WGP_F + (size_t)chunk * 104960;
  float* u    = pq + 2 * PQ_F;
  float* rwT  = u + U_F;
  float* vecs = rwT + RWT_F;
  float* h1   = vecs + 40960 + 4096 + 256;
  float* h2   = h1 + 131072;

  k_prep<<<dim3(3892), dim3(256), 0, stream>>>(pw, wGp, rw, rwT, x, c1w, c1b, hTgc);
  k_conv2<<<dim3(512), dim3(512), 0, stream>>>(hTgc, wGp, pq, 0);
  k_squash<<<dim3(256), dim3(256), 0, stream>>>(pq, pb, u);
  k_route<<<dim3(2560), dim3(512), 0, stream>>>(u, rwT, vecs);
  k_dec1<<<dim3(256), dim3(512), 0, stream>>>(vecs, w1, b1, out, h1);
  k_dec2<<<dim3(1024), dim3(128), 0, stream>>>(h1, w2, b2, h2);
  k_dec3<<<dim3(896), dim3(128), 0, stream>>>(h2, w3, b3, out + 2560);
}

// Round 19
// 705.302 us; speedup vs baseline: 1.0456x; 1.0456x over previous
//
#include <hip/hip_runtime.h>
#include <hip/hip_bf16.h>
#include <math.h>

// ---------------------------------------------------------------------------
// CapsNet forward. R19 = R18 + conv2 bank fix: hT x-stride 41 -> 43 chunks.
// Lane bank-positions (3*ox+2*oy)%8 = exactly 2 lanes per position (uniform
// 2-way = free per m136); quad tap shifts (+3 mod 8) rotate a uniform
// pattern (R10's parity failure was a non-uniform lane pattern x quad
// shifts). Costs +5% hT (LDS 55KB, still 2 blocks/CU).
// Everything else identical to R18.
// ---------------------------------------------------------------------------

typedef __attribute__((ext_vector_type(8))) short bf16x8;
typedef __attribute__((ext_vector_type(4))) float f32x4;

__device__ __forceinline__ void gl16(const void* g, void* l) {
  __builtin_amdgcn_global_load_lds((const __attribute__((address_space(1))) void*)g,
                                   (__attribute__((address_space(3))) void*)l,
                                   16, 0, 0);
}

__device__ __forceinline__ float bfl(unsigned u) {   // low bf16 -> float
  union { unsigned x; float f; } c; c.x = u << 16; return c.f;
}
__device__ __forceinline__ float bfh(unsigned u) {   // high bf16 -> float
  union { unsigned x; float f; } c; c.x = u & 0xffff0000u; return c.f;
}
__device__ __forceinline__ unsigned bpk(float a, float b) {
  const __hip_bfloat16 ha = __float2bfloat16(a), hb = __float2bfloat16(b);
  union { __hip_bfloat16 h; unsigned short s; } ca, cb;
  ca.h = ha; cb.h = hb;
  return (unsigned)ca.s | ((unsigned)cb.s << 16);
}

// hT geometry: chunk = x*43 + y*2 + half  (x<20, y<20, 3 pad chunks/x-row)
#define IC_CHUNKS 860            // 20*43
#define IC_BYTES  13760          // 860*16
#define IC_ELEMS  6880           // 860*8

// ==== k_prep: [0,2688) wrep | [2688,2868) rrep | [2868,3892) conv1 =========
__global__ __launch_bounds__(256) void k_prep(
    const float* __restrict__ pw, __hip_bfloat16* __restrict__ wGp,
    const float* __restrict__ rw, float* __restrict__ rwT,
    const float* __restrict__ x, const float* __restrict__ c1w,
    const float* __restrict__ c1b, __hip_bfloat16* __restrict__ hT) {
  __shared__ __attribute__((aligned(16))) char smem[44480];
  const int bid = blockIdx.x;
  const int t = threadIdx.x;
  if (bid < 2688) {                                 // ---- wrep ----
    const int s = bid >> 2, ocq = bid & 3;          // s in [0,672)
    const int ch = s / 21, tq = s - ch * 21;
    __hip_bfloat16* outp = wGp + ((size_t)s * 4 + ocq) * 4608;
    for (int e = t; e < 2048; e += 256) {
      const int ocl = e >> 5, k = e & 31;
      const int tapl = k >> 3, icl = k & 7;
      const int tap = tq * 4 + tapl, ic = ch * 8 + icl;
      const int oc = ocq * 64 + ocl;
      const float v = (tap < 81) ? pw[((size_t)oc * 256 + ic) * 81 + tap] : 0.f;
      const __hip_bfloat16 hi = __float2bfloat16(v);
      const __hip_bfloat16 lo = __float2bfloat16(v - __bfloat162float(hi));
      outp[ocl * 72 + k] = hi;
      outp[ocl * 72 + 32 + k] = lo;
    }
    for (int e = t; e < 512; e += 256) {
      const int ocl = e >> 3, j = e & 7;
      outp[ocl * 72 + 64 + j] = __float2bfloat16(0.f);
    }
  } else if (bid < 2868) {                          // ---- rrep ----
    // rw[o][i][c][d] -> rwT2[o][c*4+dq][i][4]  (d = dq*4+dl)
    float* tile = (float*)smem;                     // 64*129 floats (33KB)
    const int bb = bid - 2688;
    const int o = bb / 18, ig = bb % 18;
    for (int idx = t; idx < 64 * 128; idx += 256) {
      const int i = idx >> 7, cd = idx & 127;
      tile[i * 129 + cd] = rw[((size_t)o * 1152 + ig * 64 + i) * 128 + cd];
    }
    __syncthreads();
    const int il = t >> 2, dl = t & 3;              // 256 thr = 64 il x 4 dl
#pragma unroll 1
    for (int cdq = 0; cdq < 32; cdq++) {            // 1KB contiguous writes
      const int c = cdq >> 2, dq = cdq & 3;
      rwT[((size_t)(o * 32 + cdq) * 1152 + ig * 64 + il) * 4 + dl] =
          tile[il * 129 + c * 16 + dq * 4 + dl];
    }
  } else {                                          // ---- conv1 ----
    const int bb = bid - 2868;
    const int img = bb >> 2, ocq = bb & 3;          // 64 oc per block
    float* xs = (float*)smem;                       // 784 f
    float* ws = xs + 784;                           // 5184 f
    __hip_bfloat16* tile = (__hip_bfloat16*)(ws + 5184);  // 8*1288 bf16
    const float4* xg = (const float4*)(x + (size_t)img * 784);
    if (t < 196) ((float4*)xs)[t] = xg[t];
    const float4* wg = (const float4*)(c1w + (size_t)ocq * 64 * 81);
    for (int i = t; i < 1296; i += 256) ((float4*)ws)[i] = wg[i];
    __syncthreads();
    const int ocl = t & 63, rowg = t >> 6;          // wave = rowg
    const int oc = ocq * 64 + ocl;
    const int chl = ocl >> 3, icl = ocl & 7;
    const float bv = c1b[oc];
    __hip_bfloat16* hb = hT + ((size_t)img * 32 + ocq * 8) * IC_ELEMS;
#pragma unroll 1
    for (int it = 0; it < 5; it++) {
      const int r = it * 4 + rowg;                  // y
      float acc[20];
#pragma unroll
      for (int p = 0; p < 20; p++) acc[p] = bv;
#pragma unroll
      for (int ky = 0; ky < 9; ky++) {
        float xr[28];
        const float* xrow = &xs[(r + ky) * 28];
#pragma unroll
        for (int q = 0; q < 7; q++) ((float4*)xr)[q] = ((const float4*)xrow)[q];
        float wr[9];
#pragma unroll
        for (int i = 0; i < 9; i++) wr[i] = ws[ocl * 81 + ky * 9 + i];
#pragma unroll
        for (int kx = 0; kx < 9; kx++)
#pragma unroll
          for (int p = 0; p < 20; p++)
            acc[p] = fmaf(wr[kx], xr[p + kx], acc[p]);
      }
#pragma unroll
      for (int p = 0; p < 20; p++) {                // p = x
        const float v = fmaxf(acc[p], 0.f);
        const __hip_bfloat16 hi = __float2bfloat16(v);
        const __hip_bfloat16 lo = __float2bfloat16(v - __bfloat162float(hi));
        tile[chl * 1288 + (p * 8 + rowg * 2) * 8 + icl] = hi;
        tile[chl * 1288 + (p * 8 + rowg * 2 + 1) * 8 + icl] = lo;
      }
      __syncthreads();
#pragma unroll
      for (int q = 0; q < 5; q++) {                 // 1280 16B chunks
        const int idx = q * 256 + t;
        const int c2 = idx / 160, rem = idx - c2 * 160;
        const int xx = rem >> 3, j = rem & 7;
        const float4 vdat = *(const float4*)&tile[c2 * 1288 + rem * 8];
        *(float4*)(hb + (size_t)c2 * IC_ELEMS + (size_t)(xx * 43 + it * 8 + j) * 8) = vdat;
      }
      __syncthreads();
    }
  }
}

// ====== conv2 MFMA: pq[kq][img][px36][oc256] partial over 16 ch each =======
#define HT_B 55040              // 3440 chunks x 16B  (4 img x 860)
#define PQ_F 2359296
__global__ __launch_bounds__(512) void k_conv2(
    const __hip_bfloat16* __restrict__ hTg,    // [chunk img][32ch][860ch][8]
    const __hip_bfloat16* __restrict__ wGp,    // [672][4ocq][4608B] (+1 pad step)
    float* __restrict__ pq, int c0) {
  __shared__ char hT[HT_B];
  const int bid = blockIdx.x;
  int ig, ocq, kq;
  if (gridDim.x == 512) {       // XCD swizzle: ocq sharers keep bid%8
    ig = (bid & 7) | (((bid >> 5) & 7) << 3);
    ocq = (bid >> 3) & 3;
    kq = bid >> 8;
  } else {
    ig = bid >> 3;
    ocq = (bid >> 1) & 3;
    kq = bid & 1;
  }
  const int t = threadIdx.x;
  const int w = t >> 6, lane = t & 63;
  const int lquad = lane >> 4, lrow = lane & 15;
  const int mhalf = w >> 2;
  const int nt = mhalf ? 4 : 5;
  const int mtb = mhalf ? 5 : 0;
  const int ocg = ocq * 64 + (w & 3) * 16 + lrow;
  int abase[5];
#pragma unroll
  for (int i = 0; i < 5; i++) {
    int m = (mtb + i) * 16 + lrow;
    if (i >= nt) m = 0;
    const int img = m / 36, px = m - img * 36;
    const int oy = px / 6, ox = px - oy * 6;
    abase[i] = img * IC_BYTES + ox * 1376 + oy * 64;  // bytes (ox: 2*43 chunks)
  }
  f32x4 acc[5];
#pragma unroll
  for (int i = 0; i < 5; i++) acc[i] = (f32x4){0.f, 0.f, 0.f, 0.f};

  const char* hgc = (const char*)hTg;
  const char* wp = (const char*)wGp + ((size_t)(kq * 336) * 4 + ocq) * 4608 +
                   ((w & 3) * 16 + lrow) * 144 + lquad * 16;
  bf16x8 bh = *(const bf16x8*)wp;
  bf16x8 bl = *(const bf16x8*)(wp + 64);
  wp += 18432;
#pragma unroll 1
  for (int chl = 0; chl < 16; chl++) {
    const int ch = kq * 16 + chl;
    const char* hch = hgc + ((size_t)(ig * 128) + ch) * IC_BYTES;
    // stage 3440 chunks (identity copy, coalesced)
#pragma unroll
    for (int rr = 0; rr < 6; rr++) {
      const int idx = t + rr * 512;
      const int j = idx / IC_CHUNKS, r = idx - j * IC_CHUNKS;
      gl16(hch + (size_t)j * (32 * IC_BYTES) + r * 16, hT + rr * 8192 + w * 1024);
    }
    if (t < 368) {
      const int idx = 3072 + t;
      const int j = idx / IC_CHUNKS, r = idx - j * IC_CHUNKS;
      gl16(hch + (size_t)j * (32 * IC_BYTES) + r * 16, hT + 49152 + w * 1024);
    }
    __syncthreads();
#pragma unroll 1
    for (int tq = 0; tq < 21; tq++) {
      const bf16x8 nh = *(const bf16x8*)wp;         // prefetch next step's W
      const bf16x8 nl = *(const bf16x8*)(wp + 64);
      wp += 18432;
      const int tt = tq * 4 + lquad;                // this quad's tap
      const int ky = tt / 9, kx = tt - ky * 9;
      const int toff = kx * 688 + ky * 32;          // (kx*43 + ky*2) chunks
      bf16x8 ah[5];
#pragma unroll
      for (int i = 0; i < 5; i++)
        ah[i] = *(const bf16x8*)(hT + abase[i] + toff);
#pragma unroll
      for (int i = 0; i < 5; i++)
        if (i < nt) acc[i] = __builtin_amdgcn_mfma_f32_16x16x32_bf16(ah[i], bh, acc[i], 0, 0, 0);
#pragma unroll
      for (int i = 0; i < 5; i++)
        if (i < nt) acc[i] = __builtin_amdgcn_mfma_f32_16x16x32_bf16(ah[i], bl, acc[i], 0, 0, 0);
      bf16x8 al[5];
#pragma unroll
      for (int i = 0; i < 5; i++)
        al[i] = *(const bf16x8*)(hT + abase[i] + toff + 16);
#pragma unroll
      for (int i = 0; i < 5; i++)
        if (i < nt) acc[i] = __builtin_amdgcn_mfma_f32_16x16x32_bf16(al[i], bh, acc[i], 0, 0, 0);
      bh = nh;
      bl = nl;
    }
    __syncthreads();                                // hT reuse fence
  }
  float* pblk = pq + (size_t)kq * PQ_F;
#pragma unroll
  for (int i = 0; i < 5; i++) {
    if (i < nt) {
#pragma unroll
      for (int r = 0; r < 4; r++) {
        const int m = (mtb + i) * 16 + lquad * 4 + r;   // D row = quad*4+reg
        const int img = m / 36, px = m - img * 36;
        pblk[((size_t)(c0 + ig * 4 + img) * 36 + px) * 256 + ocg] = acc[i][r];
      }
    }
  }
}

// ===== squash v2: block/b, LDS-staged coalesced ============================
__global__ __launch_bounds__(256) void k_squash(const float* __restrict__ pq,
                                                const float* __restrict__ bias,
                                                float* __restrict__ u) {
  const int b = blockIdx.x;
  __shared__ float ps[36 * 257];
  const int t = threadIdx.x;
  const float4* s0 = (const float4*)(pq + (size_t)b * 9216);
  const float4* s1 = (const float4*)(pq + (size_t)PQ_F + (size_t)b * 9216);
#pragma unroll
  for (int q = 0; q < 9; q++) {                     // 2304 float4, coalesced
    const int idx = q * 256 + t;
    const float4 a = s0[idx], c = s1[idx];
    const int px = idx >> 6, oc = (idx & 63) * 4;
    float* dst = &ps[px * 257 + oc];
    dst[0] = a.x + c.x; dst[1] = a.y + c.y;
    dst[2] = a.z + c.z; dst[3] = a.w + c.w;
  }
  __syncthreads();
#pragma unroll
  for (int rr = 0; rr < 5; rr++) {
    const int i = rr * 256 + t;
    if (i < 1152) {
      const int cp = i / 36, px = i - cp * 36;
      float s[8], sq = 0.f;
#pragma unroll
      for (int d = 0; d < 8; d++) {
        s[d] = ps[px * 257 + d * 32 + cp] + bias[d * 32 + cp];
        sq = fmaf(s[d], s[d], sq);
      }
      const float scale = sq / ((1.f + sq) * sqrtf(sq));
      float o[8];
#pragma unroll
      for (int d = 0; d < 8; d++) o[d] = s[d] * scale;
      float* ub = u + ((size_t)b * 1152 + i) * 8;
      ((float4*)ub)[0] = ((float4*)o)[0];
      ((float4*)ub)[1] = ((float4*)o)[1];
    }
  }
}

// ======================= routing by agreement ==============================
__device__ __forceinline__ float wsum(float v) {
#pragma unroll
  for (int o = 32; o > 0; o >>= 1) v += __shfl_xor(v, o, 64);
  return v;
}
__device__ __forceinline__ float wmaxr(float v) {
#pragma unroll
  for (int o = 32; o > 0; o >>= 1) v = fmaxf(v, __shfl_xor(v, o, 64));
  return v;
}

// route v8: 1 img/block (grid 2560), priors bf16-packed in LDS (36.9KB) ->
// 4 blocks/CU. rwT2 b128 global loads. XCD-o-affinity swizzle.
__global__ __launch_bounds__(512, 4) void k_route(const float* __restrict__ u,
                                                  const float* __restrict__ rwT,
                                                  float* __restrict__ vecs) {
  const int bid = blockIdx.x;
  int o, b;
  if (bid < 2048) { o = bid & 7; b = bid >> 3; }         // XCD k gets o=k
  else { const int ix = bid - 2048; o = 8 + (ix & 1); b = ix >> 1; }
  __shared__ __attribute__((aligned(16))) unsigned priB[4608 * 2];  // 36.9KB
  __shared__ float red[8 * 17];
  __shared__ float redm[8];
  const int t = threadIdx.x;
  const int wave = t >> 6, lane = t & 63;
  const float* rwo = rwT + (size_t)(o * 32) * 4608;      // [cdq32][1152][4]
  const float* ub = u + (size_t)b * 9216;
  // ---- priors (fp32 compute) -> bf16-packed LDS ----
#pragma unroll
  for (int ci = 0; ci < 3; ci++) {
    const bool valid = (ci < 2) || (t < 128);
    const int i = valid ? (t + ci * 512) : 0;
    float uv[8];
    *(float4*)&uv[0] = *(const float4*)(ub + i * 8);
    *(float4*)&uv[4] = *(const float4*)(ub + i * 8 + 4);
    float a[16];
#pragma unroll
    for (int d = 0; d < 16; d++) a[d] = 0.f;
#pragma unroll
    for (int c = 0; c < 8; c++) {
#pragma unroll
      for (int dq = 0; dq < 4; dq++) {
        const float4 wv = *(const float4*)(rwo + (size_t)(c * 4 + dq) * 4608 + i * 4);
        a[dq * 4 + 0] = fmaf(uv[c], wv.x, a[dq * 4 + 0]);
        a[dq * 4 + 1] = fmaf(uv[c], wv.y, a[dq * 4 + 1]);
        a[dq * 4 + 2] = fmaf(uv[c], wv.z, a[dq * 4 + 2]);
        a[dq * 4 + 3] = fmaf(uv[c], wv.w, a[dq * 4 + 3]);
      }
    }
    if (valid) {
#pragma unroll
      for (int dq = 0; dq < 4; dq++) {
        uint2 p;
        p.x = bpk(a[dq * 4 + 0], a[dq * 4 + 1]);
        p.y = bpk(a[dq * 4 + 2], a[dq * 4 + 3]);
        *(uint2*)&priB[(dq * 1152 + i) * 2] = p;    // 8B dense -> no conflict
      }
    }
  }
  __syncthreads();
  float l[3];
#pragma unroll
  for (int ci = 0; ci < 3; ci++)
    l[ci] = ((ci < 2) || (t < 128)) ? 0.f : -1e30f;
  float v[16];
#pragma unroll 1
  for (int it = 0; it < 3; it++) {
    float m = wmaxr(fmaxf(fmaxf(l[0], l[1]), l[2]));
    if (lane == 0) redm[wave] = m;
    __syncthreads();
    m = redm[0];
#pragma unroll
    for (int wv2 = 1; wv2 < 8; wv2++) m = fmaxf(m, redm[wv2]);
    float Z = 0.f, S[16];
#pragma unroll
    for (int d = 0; d < 16; d++) S[d] = 0.f;
#pragma unroll
    for (int ci = 0; ci < 3; ci++) {
      const bool valid = (ci < 2) || (t < 128);
      const int i = valid ? (t + ci * 512) : 0;
      const float e = expf(l[ci] - m);               // 0 for dummies
      Z += e;
#pragma unroll
      for (int dq = 0; dq < 4; dq++) {
        const uint2 w = *(const uint2*)&priB[(dq * 1152 + i) * 2];
        S[dq * 4 + 0] = fmaf(e, bfl(w.x), S[dq * 4 + 0]);
        S[dq * 4 + 1] = fmaf(e, bfh(w.x), S[dq * 4 + 1]);
        S[dq * 4 + 2] = fmaf(e, bfl(w.y), S[dq * 4 + 2]);
        S[dq * 4 + 3] = fmaf(e, bfh(w.y), S[dq * 4 + 3]);
      }
    }
    Z = wsum(Z);
#pragma unroll
    for (int d = 0; d < 16; d++) S[d] = wsum(S[d]);
    __syncthreads();                                 // red reuse fence
    if (lane == 0) {
      red[wave * 17] = Z;
#pragma unroll
      for (int d = 0; d < 16; d++) red[wave * 17 + 1 + d] = S[d];
    }
    __syncthreads();
    float Zt = 0.f;
#pragma unroll
    for (int wv2 = 0; wv2 < 8; wv2++) Zt += red[wv2 * 17];
    float sq = 0.f;
#pragma unroll
    for (int d = 0; d < 16; d++) {
      float sd = 0.f;
#pragma unroll
      for (int wv2 = 0; wv2 < 8; wv2++) sd += red[wv2 * 17 + 1 + d];
      sd /= Zt;
      v[d] = sd;
      sq = fmaf(sd, sd, sq);
    }
    const float scale = sq / ((1.f + sq) * sqrtf(sq));
#pragma unroll
    for (int d = 0; d < 16; d++) v[d] *= scale;
    if (it < 2) {
#pragma unroll
      for (int ci = 0; ci < 3; ci++) {
        const bool valid = (ci < 2) || (t < 128);
        const int i = valid ? (t + ci * 512) : 0;
        float dot = 0.f;
#pragma unroll
        for (int dq = 0; dq < 4; dq++) {
          const uint2 w = *(const uint2*)&priB[(dq * 1152 + i) * 2];
          dot = fmaf(bfl(w.x), v[dq * 4 + 0], dot);
          dot = fmaf(bfh(w.x), v[dq * 4 + 1], dot);
          dot = fmaf(bfl(w.y), v[dq * 4 + 2], dot);
          dot = fmaf(bfh(w.y), v[dq * 4 + 3], dot);
        }
        l[ci] += dot;
      }
    }
  }
  if (t == 0) {
    float* vb = vecs + ((size_t)b * 10 + o) * 16;
#pragma unroll
    for (int d = 0; d < 16; d++) vb[d] = v[d];
  }
}

// ====== dec1 (cls fused): classes softmax/argmax + first decoder layer =====
__global__ __launch_bounds__(512) void k_dec1(const float* __restrict__ vecs,
                                              const float* __restrict__ w1,
                                              const float* __restrict__ b1,
                                              float* __restrict__ out,
                                              float* __restrict__ h1) {
  const int b = blockIdx.x, t = threadIdx.x;
  __shared__ float vbs[160];
  __shared__ float sv[16];
  __shared__ int ams;
  const float* vb = vecs + (size_t)b * 160;
  if (t < 160) vbs[t] = vb[t];                      // coalesced
  __syncthreads();
  if (t == 0) {
    float nrm[10];
#pragma unroll
    for (int o = 0; o < 10; o++) {
      float sq = 0.f;
#pragma unroll
      for (int d = 0; d < 16; d++) { const float xv = vbs[o * 16 + d]; sq = fmaf(xv, xv, sq); }
      nrm[o] = sqrtf(sq);
    }
    float m = nrm[0];
#pragma unroll
    for (int o = 1; o < 10; o++) m = fmaxf(m, nrm[o]);
    float e[10], Z = 0.f;
#pragma unroll
    for (int o = 0; o < 10; o++) { e[o] = expf(nrm[o] - m); Z += e[o]; }
    const float inv = 1.f / Z;
    int am = 0;
    float best = e[0] * inv;
#pragma unroll
    for (int o = 0; o < 10; o++) {
      const float c = e[o] * inv;
      out[(size_t)b * 10 + o] = c;
      if (o > 0 && c > best) { best = c; am = o; }  // strict >: first-max
    }
    ams = am;
  }
  __syncthreads();
  const int am2 = ams;
  if (t < 16) sv[t] = vbs[am2 * 16 + t];
  __syncthreads();
  const float* wrow = w1 + (size_t)am2 * 16 * 512;
  float acc = b1[t];
#pragma unroll
  for (int d = 0; d < 16; d++) acc = fmaf(sv[d], wrow[d * 512 + t], acc);
  h1[(size_t)b * 512 + t] = fmaxf(acc, 0.f);
}

// dec2 v2: 2 imgs x 128 n per block (grid 1024); w2 in 32-k LDS tiles.
__global__ __launch_bounds__(128) void k_dec2(const float* __restrict__ h1,
                                              const float* __restrict__ w2,
                                              const float* __restrict__ b2,
                                              float* __restrict__ h2) {
  const int nc = blockIdx.x >> 7, bg = blockIdx.x & 127;
  const int t = threadIdx.x;
  const int n = nc * 128 + t;
  const int bs = bg * 2;
  __shared__ float h1s[2 * 512];
  __shared__ float wts[32 * 128];
  {
    const float4* src = (const float4*)(h1 + (size_t)bs * 512);
    for (int i = t; i < 256; i += 128) ((float4*)h1s)[i] = src[i];
  }
  float acc[2];
  const float bb = b2[n];
  acc[0] = bb; acc[1] = bb;
#pragma unroll 1
  for (int kt = 0; kt < 16; kt++) {
    __syncthreads();
#pragma unroll
    for (int r = 0; r < 32; r++)
      wts[r * 128 + t] = w2[(size_t)(kt * 32 + r) * 1024 + n];
    __syncthreads();
#pragma unroll
    for (int k4 = 0; k4 < 8; k4++) {
      float wq[4];
#pragma unroll
      for (int q = 0; q < 4; q++) wq[q] = wts[(k4 * 4 + q) * 128 + t];
#pragma unroll
      for (int j = 0; j < 2; j++) {
        const float4 hv = *(const float4*)&h1s[j * 512 + kt * 32 + k4 * 4];
        acc[j] = fmaf(hv.x, wq[0], acc[j]);
        acc[j] = fmaf(hv.y, wq[1], acc[j]);
        acc[j] = fmaf(hv.z, wq[2], acc[j]);
        acc[j] = fmaf(hv.w, wq[3], acc[j]);
      }
    }
  }
#pragma unroll
  for (int j = 0; j < 2; j++) h2[(size_t)(bs + j) * 1024 + n] = fmaxf(acc[j], 0.f);
}

// dec3 v2: 2 imgs x 112 n per block (grid 896); w3 in 32-k LDS tiles.
__global__ __launch_bounds__(128) void k_dec3(const float* __restrict__ h2,
                                              const float* __restrict__ w3,
                                              const float* __restrict__ b3,
                                              float* __restrict__ out) {
  const int nc = blockIdx.x >> 7, bg = blockIdx.x & 127;
  const int t = threadIdx.x;
  const int bs = bg * 2;
  __shared__ float h2s[2 * 1024];
  __shared__ float wts[32 * 112];
  {
    const float4* src = (const float4*)(h2 + (size_t)bs * 1024);
    for (int i = t; i < 512; i += 128) ((float4*)h2s)[i] = src[i];
  }
  const int n = nc * 112 + (t < 112 ? t : 0);
  float acc[2];
  const float bb = b3[n];
  acc[0] = bb; acc[1] = bb;
#pragma unroll 1
  for (int kt = 0; kt < 32; kt++) {
    __syncthreads();
#pragma unroll
    for (int r = 0; r < 32; r++)
      if (t < 112) wts[r * 112 + t] = w3[(size_t)(kt * 32 + r) * 784 + n];
    __syncthreads();
    if (t < 112) {
#pragma unroll
      for (int k4 = 0; k4 < 8; k4++) {
        float wq[4];
#pragma unroll
        for (int q = 0; q < 4; q++) wq[q] = wts[(k4 * 4 + q) * 112 + t];
#pragma unroll
        for (int j = 0; j < 2; j++) {
          const float4 hv = *(const float4*)&h2s[j * 1024 + kt * 32 + k4 * 4];
          acc[j] = fmaf(hv.x, wq[0], acc[j]);
          acc[j] = fmaf(hv.y, wq[1], acc[j]);
          acc[j] = fmaf(hv.z, wq[2], acc[j]);
          acc[j] = fmaf(hv.w, wq[3], acc[j]);
        }
      }
    }
  }
  if (t < 112) {
#pragma unroll
    for (int j = 0; j < 2; j++)
      out[(size_t)(bs + j) * 784 + n] = 1.f / (1.f + expf(-acc[j]));
  }
}

// ============================= launcher ====================================
extern "C" void kernel_launch(void* const* d_in, const int* in_sizes, int n_in,
                              void* d_out, int out_size, void* d_ws, size_t ws_size,
                              hipStream_t stream) {
  const float* x   = (const float*)d_in[0];
  const float* c1w = (const float*)d_in[1];
  const float* c1b = (const float*)d_in[2];
  const float* pw  = (const float*)d_in[3];
  const float* pb  = (const float*)d_in[4];
  const float* rw  = (const float*)d_in[5];
  const float* w1  = (const float*)d_in[6];
  const float* b1  = (const float*)d_in[7];
  const float* w2  = (const float*)d_in[8];
  const float* b2  = (const float*)d_in[9];
  const float* w3  = (const float*)d_in[10];
  const float* b3  = (const float*)d_in[11];
  float* out = (float*)d_out;
  float* ws = (float*)d_ws;

  const size_t WGP_F = ((size_t)672 * 4 * 4608 + 18432) / 4;
  const size_t U_F = 2359296;
  const size_t RWT_F = 10 * 32 * 4608;                 // rwT2 layout
  const size_t SMALL_F = 40960 + 4096 + 256 + 131072 + 262144;
  const size_t fixed_f = WGP_F + 2 * PQ_F + U_F + RWT_F + SMALL_F;
  // hTgc floats per img: 32ch * 860 chunks * 16B / 4 = 110080
  int chunk = 256;
  while (chunk > 8 && (fixed_f + (size_t)chunk * 110080) * 4 > ws_size) chunk >>= 1;

  __hip_bfloat16* wGp  = (__hip_bfloat16*)ws;
  __hip_bfloat16* hTgc = (__hip_bfloat16*)(ws + WGP_F);
  float* pq   = ws + WGP_F + (size_t)chunk * 110080;
  float* u    = pq + 2 * PQ_F;
  float* rwT  = u + U_F;
  float* vecs = rwT + RWT_F;
  float* h1   = vecs + 40960 + 4096 + 256;
  float* h2   = h1 + 131072;

  k_prep<<<dim3(3892), dim3(256), 0, stream>>>(pw, wGp, rw, rwT, x, c1w, c1b, hTgc);
  k_conv2<<<dim3(512), dim3(512), 0, stream>>>(hTgc, wGp, pq, 0);
  k_squash<<<dim3(256), dim3(256), 0, stream>>>(pq, pb, u);
  k_route<<<dim3(2560), dim3(512), 0, stream>>>(u, rwT, vecs);
  k_dec1<<<dim3(256), dim3(512), 0, stream>>>(vecs, w1, b1, out, h1);
  k_dec2<<<dim3(1024), dim3(128), 0, stream>>>(h1, w2, b2, h2);
  k_dec3<<<dim3(896), dim3(128), 0, stream>>>(h2, w3, b3, out + 2560);
}